// Round 1
// 1193.449 us; speedup vs baseline: 1.2723x; 1.2723x over previous
//
#include <hip/hip_runtime.h>
#include <hip/hip_bf16.h>

#define N_USERS 100000
#define N_ITEMS 50000
#define N_TOTAL 150000
#define IN_DIM 768
#define BRANCH 64
#define N_EDGES 2097152
#define BATCH 4096
#define NUM_CAND 128
#define NEG 16
#define TEMP 0.1f
#define D2 128

#define SCAN_CHUNK 1024
#define SCAN_BLOCKS ((N_TOTAL + SCAN_CHUNK - 1) / SCAN_CHUNK)  // 147

typedef short short8 __attribute__((ext_vector_type(8)));
typedef float f32x4 __attribute__((ext_vector_type(4)));

__device__ __forceinline__ unsigned short f2bf(float f) {
    unsigned int u = __builtin_bit_cast(unsigned int, f);
    u += 0x7fffu + ((u >> 16) & 1u);   // round-to-nearest-even
    return (unsigned short)(u >> 16);
}

// ---------------- CSR build ----------------

__global__ __launch_bounds__(256) void hist_kernel(const int* __restrict__ rows,
                                                   int* __restrict__ counts) {
    int i = blockIdx.x * blockDim.x + threadIdx.x;
    int stride = gridDim.x * blockDim.x;
    for (; i < N_EDGES; i += stride) atomicAdd(&counts[rows[i]], 1);
}

__global__ __launch_bounds__(256) void scan_partial(const int* __restrict__ counts,
                                                    int* __restrict__ bs) {
    int t = threadIdx.x;
    long fi = ((long)blockIdx.x * 256 + t) * 4;
    int4 v = {0, 0, 0, 0};
    if (fi < N_TOTAL) v = *(const int4*)(counts + fi);  // N_TOTAL % 4 == 0
    int s = v.x + v.y + v.z + v.w;
    #pragma unroll
    for (int off = 1; off < 64; off <<= 1) s += __shfl_xor(s, off);
    __shared__ int wsum[4];
    int lane = t & 63, wid = t >> 6;
    if (lane == 0) wsum[wid] = s;
    __syncthreads();
    if (t == 0) bs[blockIdx.x] = wsum[0] + wsum[1] + wsum[2] + wsum[3];
}

__global__ __launch_bounds__(256) void scan_blocksums(int* __restrict__ bs,
                                                      int* __restrict__ offs) {
    int t = threadIdx.x;
    int x = (t < SCAN_BLOCKS) ? bs[t] : 0;
    int orig = x;
    int lane = t & 63, wid = t >> 6;
    #pragma unroll
    for (int off = 1; off < 64; off <<= 1) {
        int y = __shfl_up(x, off);
        if (lane >= off) x += y;
    }
    __shared__ int wsum[4], woff[4];
    if (lane == 63) wsum[wid] = x;
    __syncthreads();
    if (t == 0) {
        int r = 0;
        for (int i = 0; i < 4; ++i) { woff[i] = r; r += wsum[i]; }
    }
    __syncthreads();
    int incl = x + woff[wid];
    if (t < SCAN_BLOCKS) bs[t] = incl - orig;        // exclusive prefix
    if (t == SCAN_BLOCKS - 1) offs[N_TOTAL] = incl;  // total == N_EDGES
}

__global__ __launch_bounds__(256) void scan_final(const int* __restrict__ bs,
                                                  int* __restrict__ offs,
                                                  int* __restrict__ cur) {
    int t = threadIdx.x;
    long fi = ((long)blockIdx.x * 256 + t) * 4;
    int4 v = {0, 0, 0, 0};
    bool ok = fi < N_TOTAL;
    if (ok) v = *(const int4*)(offs + fi);
    int s = v.x + v.y + v.z + v.w;
    int x = s;
    int lane = t & 63, wid = t >> 6;
    #pragma unroll
    for (int off = 1; off < 64; off <<= 1) {
        int y = __shfl_up(x, off);
        if (lane >= off) x += y;
    }
    __shared__ int wsum[4], woff[4];
    if (lane == 63) wsum[wid] = x;
    __syncthreads();
    if (t == 0) {
        int r = 0;
        for (int i = 0; i < 4; ++i) { woff[i] = r; r += wsum[i]; }
    }
    __syncthreads();
    int excl = (x - s) + woff[wid] + bs[blockIdx.x];
    if (ok) {
        int4 o;
        o.x = excl;
        o.y = o.x + v.x;
        o.z = o.y + v.y;
        o.w = o.z + v.z;
        *(int4*)(offs + fi) = o;
        *(int4*)(cur + fi)  = o;
    }
}

// packed edge record: .x = col, .y = float bits of val  (one 8B store per edge,
// halves the random-line touches vs two 4B stores into separate arrays)
__global__ __launch_bounds__(256) void scatter_kernel(const int* __restrict__ rows,
                                                      const int* __restrict__ cols,
                                                      const float* __restrict__ vals,
                                                      int* __restrict__ cur,
                                                      int2* __restrict__ edges) {
    int i = blockIdx.x * blockDim.x + threadIdx.x;
    int stride = gridDim.x * blockDim.x;
    for (; i < N_EDGES; i += stride) {
        int r = rows[i];
        int p = atomicAdd(&cur[r], 1);
        edges[p] = make_int2(cols[i], __float_as_int(vals[i]));
    }
}

// ---------------- GCN ----------------

__global__ __launch_bounds__(256) void init_ego_kernel(const float* __restrict__ uw,
                                                       const float* __restrict__ iw,
                                                       float* __restrict__ ego,
                                                       float* __restrict__ acc) {
    long i = (long)blockIdx.x * blockDim.x + threadIdx.x;  // float4 index
    const long n4 = (long)N_TOTAL * BRANCH / 4;
    if (i >= n4) return;
    long fi = i * 4;
    const long usz = (long)N_USERS * BRANCH;
    float4 v;
    if (fi < usz) v = *(const float4*)(uw + fi);
    else          v = *(const float4*)(iw + (fi - usz));
    *(float4*)(ego + fi) = v;
    *(float4*)(acc + fi) = v;
}

// 4 rows per wave (16 lanes x float4 each): one dwordx4 gather instruction keeps
// 4 independent 256B row-segments in flight; edge loop unrolled x4 on top of that
// -> up to 16 concurrent gather streams per wave (vs 1 in the row-per-wave version).
__global__ __launch_bounds__(256) void spmv_kernel(const int* __restrict__ offs,
                                                   const int2* __restrict__ edges,
                                                   const float* __restrict__ ego_in,
                                                   float* __restrict__ ego_out,
                                                   float* __restrict__ acc,
                                                   int write_ego) {
    int wave = (blockIdx.x * 256 + threadIdx.x) >> 6;
    int lane = threadIdx.x & 63;
    int sub  = lane >> 4;          // which of the 4 rows in this wave
    int l16  = lane & 15;          // float4 slot within the row (16*4 = 64 dims)
    int row  = wave * 4 + sub;
    if (row >= N_TOTAL) return;

    int s = offs[row], e = offs[row + 1];
    f32x4 sum = {0.f, 0.f, 0.f, 0.f};

    int i  = s;
    int e4 = s + ((e - s) & ~3);
    for (; i < e4; i += 4) {
        int2 p0 = edges[i];
        int2 p1 = edges[i + 1];
        int2 p2 = edges[i + 2];
        int2 p3 = edges[i + 3];
        f32x4 g0 = *(const f32x4*)(ego_in + (long)p0.x * BRANCH + l16 * 4);
        f32x4 g1 = *(const f32x4*)(ego_in + (long)p1.x * BRANCH + l16 * 4);
        f32x4 g2 = *(const f32x4*)(ego_in + (long)p2.x * BRANCH + l16 * 4);
        f32x4 g3 = *(const f32x4*)(ego_in + (long)p3.x * BRANCH + l16 * 4);
        sum += g0 * __int_as_float(p0.y);
        sum += g1 * __int_as_float(p1.y);
        sum += g2 * __int_as_float(p2.y);
        sum += g3 * __int_as_float(p3.y);
    }
    for (; i < e; ++i) {
        int2 p = edges[i];
        f32x4 g = *(const f32x4*)(ego_in + (long)p.x * BRANCH + l16 * 4);
        sum += g * __int_as_float(p.y);
    }

    long o = (long)row * BRANCH + l16 * 4;       // 4 consecutive rows -> 1KB coalesced
    if (write_ego) *(f32x4*)(ego_out + o) = sum; // dead on last layer, skip
    f32x4 a = *(const f32x4*)(acc + o);
    a += sum;
    *(f32x4*)(acc + o) = a;
}

// ---------------- semantic branch: bf16 MFMA GEMM ----------------

__global__ __launch_bounds__(256) void wt_prep(const float* __restrict__ W,
                                               unsigned short* __restrict__ gWt) {
    int idx = blockIdx.x * 256 + threadIdx.x;  // over 64*768
    if (idx >= 64 * IN_DIM) return;
    int n = idx / IN_DIM, k = idx % IN_DIM;
    gWt[idx] = f2bf(W[(long)k * 64 + n]);
}

#define GROWS 128
#define GK 32
#define LSTR 40   // padded LDS row stride (bf16 elems): 80 B, 16B-aligned, conflict-free b128 reads

__global__ __launch_bounds__(256) void sem_gemm_mfma(const float* __restrict__ user_base,
                                                     const float* __restrict__ item_base,
                                                     const unsigned short* __restrict__ gWt,
                                                     const float* __restrict__ bias,
                                                     float* __restrict__ all_emb) {
    __shared__ unsigned short Asl[GROWS * LSTR];  // [row][k] 10 KB
    __shared__ unsigned short Wsl[64 * LSTR];     // [n][k]   5 KB

    const int tid  = threadIdx.x;
    const int row0 = blockIdx.x * GROWS;
    const int wv   = tid >> 6;
    const int lane = tid & 63;
    const int l15  = lane & 15;
    const int quad = lane >> 4;

    const int s_r = tid >> 3;        // 0..31
    const int s_c = (tid & 7) * 4;   // 0..28

    f32x4 acc[2][4];
    #pragma unroll
    for (int r = 0; r < 2; ++r)
        #pragma unroll
        for (int c = 0; c < 4; ++c)
            acc[r][c] = (f32x4){0.f, 0.f, 0.f, 0.f};

    const int wt_n  = tid >> 2;
    const int wt_c8 = (tid & 3) * 8;

    for (int kt = 0; kt < IN_DIM; kt += GK) {
        // stage A (fp32 -> bf16)
        #pragma unroll
        for (int i = 0; i < 4; ++i) {
            int r = s_r + i * 32;
            int gr = row0 + r;
            if (gr >= N_TOTAL) gr = 0;
            const float* src = (gr < N_USERS) ? (user_base + (long)gr * IN_DIM)
                                              : (item_base + (long)(gr - N_USERS) * IN_DIM);
            float4 v = *(const float4*)(src + kt + s_c);
            unsigned short* d = &Asl[r * LSTR + s_c];
            d[0] = f2bf(v.x); d[1] = f2bf(v.y); d[2] = f2bf(v.z); d[3] = f2bf(v.w);
        }
        // stage Wt (already bf16): 16 B per thread
        {
            uint4 v = *(const uint4*)(gWt + (long)wt_n * IN_DIM + kt + wt_c8);
            *(uint4*)(&Wsl[wt_n * LSTR + wt_c8]) = v;
        }
        __syncthreads();

        const int arow = wv * 32 + l15;
        short8 a0 = *(const short8*)(&Asl[arow * LSTR + quad * 8]);
        short8 a1 = *(const short8*)(&Asl[(arow + 16) * LSTR + quad * 8]);
        short8 b[4];
        #pragma unroll
        for (int c = 0; c < 4; ++c)
            b[c] = *(const short8*)(&Wsl[(c * 16 + l15) * LSTR + quad * 8]);
        #pragma unroll
        for (int c = 0; c < 4; ++c) {
            acc[0][c] = __builtin_amdgcn_mfma_f32_16x16x32_bf16(a0, b[c], acc[0][c], 0, 0, 0);
            acc[1][c] = __builtin_amdgcn_mfma_f32_16x16x32_bf16(a1, b[c], acc[1][c], 0, 0, 0);
        }
        __syncthreads();
    }

    // epilogue: D[row][col] -> all_emb[row][64+col] + bias
    #pragma unroll
    for (int r = 0; r < 2; ++r) {
        #pragma unroll
        for (int c = 0; c < 4; ++c) {
            int col = c * 16 + l15;
            float bv = bias[col];
            #pragma unroll
            for (int i = 0; i < 4; ++i) {
                int gr = row0 + wv * 32 + r * 16 + quad * 4 + i;
                if (gr < N_TOTAL)
                    all_emb[(long)gr * D2 + BRANCH + col] = acc[r][c][i] + bv;
            }
        }
    }
}

// ---------------- fusion ----------------

__global__ __launch_bounds__(256) void fuse_kernel(const float* __restrict__ acc,
                                                   float* __restrict__ all_emb) {
    int wave = (blockIdx.x * 256 + threadIdx.x) >> 6;
    int lane = threadIdx.x & 63;
    if (wave >= N_TOTAL) return;

    float c = acc[(long)wave * BRANCH + lane] * 0.25f;
    float cs = c * c;
    #pragma unroll
    for (int off = 1; off < 64; off <<= 1) cs += __shfl_xor(cs, off);
    float cn = c / fmaxf(sqrtf(cs), 1e-12f);

    float s = all_emb[(long)wave * D2 + BRANCH + lane];
    float ss = s * s;
    #pragma unroll
    for (int off = 1; off < 64; off <<= 1) ss += __shfl_xor(ss, off);
    float sn = s / fmaxf(sqrtf(ss), 1e-12f);

    float tt = cn * cn + sn * sn;
    #pragma unroll
    for (int off = 1; off < 64; off <<= 1) tt += __shfl_xor(tt, off);
    float inv = 1.0f / fmaxf(sqrtf(tt), 1e-12f);

    all_emb[(long)wave * D2 + lane]          = cn * inv;
    all_emb[(long)wave * D2 + BRANCH + lane] = sn * inv;
}

// ---------------- batch scoring + top-16 + loss ----------------

__global__ __launch_bounds__(128) void loss_kernel(const float* __restrict__ all_emb,
                                                   const int* __restrict__ uids,
                                                   const int* __restrict__ pos_iids,
                                                   const int* __restrict__ cand_ids,
                                                   float* __restrict__ out) {
    __shared__ __align__(16) float uL[128];
    __shared__ float sc[128];
    __shared__ float redv[128];
    __shared__ int   ridx[128];
    __shared__ float topvals[NEG];

    int b = blockIdx.x;
    int t = threadIdx.x;
    int uid = uids[b];
    int pid = pos_iids[b];
    const float* ib = all_emb + (long)N_USERS * D2;

    uL[t] = all_emb[(long)uid * D2 + t];
    __syncthreads();

    redv[t] = uL[t] * ib[(long)pid * D2 + t];
    __syncthreads();
    for (int st = 64; st > 0; st >>= 1) {
        if (t < st) redv[t] += redv[t + st];
        __syncthreads();
    }
    float pos_dot = redv[0];

    int cand = cand_ids[(long)b * NUM_CAND + t];
    if (cand == pid) cand = (cand + 1) % N_ITEMS;
    const float4* cr4 = (const float4*)(ib + (long)cand * D2);
    const float4* u4  = (const float4*)uL;
    float s = 0.f;
    #pragma unroll 8
    for (int k = 0; k < 32; ++k) {
        float4 a = cr4[k];
        float4 u = u4[k];
        s += a.x * u.x + a.y * u.y + a.z * u.z + a.w * u.w;
    }
    sc[t] = s;
    __syncthreads();

    for (int it = 0; it < NEG; ++it) {
        redv[t] = sc[t];
        ridx[t] = t;
        __syncthreads();
        for (int st = 64; st > 0; st >>= 1) {
            if (t < st) {
                if (redv[t + st] > redv[t]) { redv[t] = redv[t + st]; ridx[t] = ridx[t + st]; }
            }
            __syncthreads();
        }
        if (t == 0) {
            topvals[it] = redv[0];
            sc[ridx[0]] = -3.0e38f;
        }
        __syncthreads();
    }

    if (t == 0) {
        float pl = pos_dot / TEMP;
        float m = pl;
        #pragma unroll
        for (int i = 0; i < NEG; ++i) m = fmaxf(m, topvals[i] / TEMP);
        float se = __expf(pl - m);
        #pragma unroll
        for (int i = 0; i < NEG; ++i) se += __expf(topvals[i] / TEMP - m);
        float lse = m + __logf(se);
        atomicAdd(out, (lse - pl) * (1.0f / BATCH));
    }
}

// ---------------- launch ----------------

extern "C" void kernel_launch(void* const* d_in, const int* in_sizes, int n_in,
                              void* d_out, int out_size, void* d_ws, size_t ws_size,
                              hipStream_t stream) {
    const float* raw_item_embs = (const float*)d_in[0];
    const float* user_sem_base = (const float*)d_in[1];
    const float* sem_w         = (const float*)d_in[2];
    const float* sem_b         = (const float*)d_in[3];
    const float* collab_user_w = (const float*)d_in[4];
    const float* collab_item_w = (const float*)d_in[5];
    const float* adj_vals      = (const float*)d_in[6];
    const int*   adj_rows      = (const int*)d_in[7];
    const int*   adj_cols      = (const int*)d_in[8];
    const int*   uids          = (const int*)d_in[9];
    const int*   pos_iids      = (const int*)d_in[10];
    const int*   cand_ids      = (const int*)d_in[11];
    float* out = (float*)d_out;

    float* all_emb = (float*)d_ws;                           // 150000*128
    float* acc     = all_emb + (long)N_TOTAL * D2;           // 150000*64
    float* egoA    = acc  + (long)N_TOTAL * BRANCH;
    float* egoB    = egoA + (long)N_TOTAL * BRANCH;
    int*   offs    = (int*)(egoB + (long)N_TOTAL * BRANCH);  // N_TOTAL+1
    int*   cur     = offs + (N_TOTAL + 4);                   // keep 16B alignment
    int2*  edges   = (int2*)(cur + N_TOTAL);                 // N_EDGES packed (col,val)
    int*   bsums   = (int*)(edges + N_EDGES);                // SCAN_BLOCKS (pad to 256)
    unsigned short* gWt = (unsigned short*)(bsums + 256);    // 64*768 bf16

    hipMemsetAsync(offs, 0, (N_TOTAL + 1) * sizeof(int), stream);
    hipMemsetAsync(out, 0, sizeof(float), stream);

    // CSR build
    hist_kernel<<<4096, 256, 0, stream>>>(adj_rows, offs);
    scan_partial<<<SCAN_BLOCKS, 256, 0, stream>>>(offs, bsums);
    scan_blocksums<<<1, 256, 0, stream>>>(bsums, offs);
    scan_final<<<SCAN_BLOCKS, 256, 0, stream>>>(bsums, offs, cur);
    scatter_kernel<<<4096, 256, 0, stream>>>(adj_rows, adj_cols, adj_vals, cur, edges);

    // GCN
    init_ego_kernel<<<(N_TOTAL * BRANCH / 4 + 255) / 256, 256, 0, stream>>>(
        collab_user_w, collab_item_w, egoA, acc);
    const int spmv_blocks = (N_TOTAL + 15) / 16;  // 4 rows/wave, 4 waves/block -> 9375
    spmv_kernel<<<spmv_blocks, 256, 0, stream>>>(offs, edges, egoA, egoB, acc, 1);
    spmv_kernel<<<spmv_blocks, 256, 0, stream>>>(offs, edges, egoB, egoA, acc, 1);
    spmv_kernel<<<spmv_blocks, 256, 0, stream>>>(offs, edges, egoA, egoB, acc, 0);

    // semantic branch (bf16 MFMA)
    wt_prep<<<(64 * IN_DIM + 255) / 256, 256, 0, stream>>>(sem_w, gWt);
    sem_gemm_mfma<<<(N_TOTAL + GROWS - 1) / GROWS, 256, 0, stream>>>(
        user_sem_base, raw_item_embs, gWt, sem_b, all_emb);

    // fusion
    fuse_kernel<<<37500, 256, 0, stream>>>(acc, all_emb);

    // loss
    loss_kernel<<<BATCH, 128, 0, stream>>>(all_emb, uids, pos_iids, cand_ids, out);
}

// Round 2
// 1049.717 us; speedup vs baseline: 1.4465x; 1.1369x over previous
//
#include <hip/hip_runtime.h>
#include <hip/hip_bf16.h>

#define N_USERS 100000
#define N_ITEMS 50000
#define N_TOTAL 150000
#define IN_DIM 768
#define BRANCH 64
#define N_EDGES 2097152
#define BATCH 4096
#define NUM_CAND 128
#define NEG 16
#define TEMP 0.1f
#define D2 128

// bucketed CSR build: 256 rows per bucket
#define NB 586                     // ceil(150000 / 256)
#define BH_BLOCKS 1024             // 1024 blocks * 256 thr * 8 edges = 2^21 = N_EDGES

typedef short short8 __attribute__((ext_vector_type(8)));
typedef float f32x4 __attribute__((ext_vector_type(4)));

__device__ __forceinline__ unsigned short f2bf(float f) {
    unsigned int u = __builtin_bit_cast(unsigned int, f);
    u += 0x7fffu + ((u >> 16) & 1u);   // round-to-nearest-even
    return (unsigned short)(u >> 16);
}

// ---------------- bucketed CSR build ----------------
// All high-contention work is LDS-local; global atomics are one-per-(block,bucket).

__global__ __launch_bounds__(256) void bucket_hist(const int* __restrict__ rows,
                                                   int* __restrict__ bcnt) {
    __shared__ int h[NB];
    int t = threadIdx.x;
    long base = (long)blockIdx.x * 2048;
    for (int b = t; b < NB; b += 256) h[b] = 0;
    __syncthreads();
    #pragma unroll
    for (int k = 0; k < 8; ++k)
        atomicAdd(&h[rows[base + k * 256 + t] >> 8], 1);
    __syncthreads();
    for (int b = t; b < NB; b += 256) {
        int c = h[b];
        if (c) atomicAdd(&bcnt[b], c);
    }
}

// single block: exclusive scan of 586 bucket counts -> boff (NB+1), bcur copy,
// also writes offs[N_TOTAL] = N_EDGES
__global__ __launch_bounds__(256) void bucket_scan(const int* __restrict__ bcnt,
                                                   int* __restrict__ boff,
                                                   int* __restrict__ bcur,
                                                   int* __restrict__ offs) {
    int t = threadIdx.x;
    int fi = t * 4;
    int a0 = (fi + 0 < NB) ? bcnt[fi + 0] : 0;
    int a1 = (fi + 1 < NB) ? bcnt[fi + 1] : 0;
    int a2 = (fi + 2 < NB) ? bcnt[fi + 2] : 0;
    int a3 = (fi + 3 < NB) ? bcnt[fi + 3] : 0;
    int sm = a0 + a1 + a2 + a3;
    int x = sm;
    int lane = t & 63, wid = t >> 6;
    #pragma unroll
    for (int off = 1; off < 64; off <<= 1) {
        int y = __shfl_up(x, off);
        if (lane >= off) x += y;
    }
    __shared__ int wsum[4], woff[4];
    if (lane == 63) wsum[wid] = x;
    __syncthreads();
    if (t == 0) {
        int r = 0;
        for (int i = 0; i < 4; ++i) { woff[i] = r; r += wsum[i]; }
    }
    __syncthreads();
    int excl = (x - sm) + woff[wid];
    int p[5];
    p[0] = excl;
    p[1] = p[0] + a0;
    p[2] = p[1] + a1;
    p[3] = p[2] + a2;
    p[4] = p[3] + a3;
    #pragma unroll
    for (int k = 0; k < 4; ++k) {
        if (fi + k < NB) { boff[fi + k] = p[k]; bcur[fi + k] = p[k]; }
    }
    if (fi <= NB && NB < fi + 4) {       // thread holding index NB writes the total
        boff[NB] = p[NB - fi];
        offs[N_TOTAL] = p[NB - fi];      // == N_EDGES
    }
}

// partition edges into buckets; per-block chunk reservation keeps each
// (block,bucket) group contiguous -> near-sequential line writes.
// record: .x = (row_local<8b> << 18) | col<18b>, .y = val bits
__global__ __launch_bounds__(256) void bucket_scatter(const int* __restrict__ rows,
                                                      const int* __restrict__ cols,
                                                      const float* __restrict__ vals,
                                                      int* __restrict__ bcur,
                                                      int2* __restrict__ bedges) {
    __shared__ int lcnt[NB];
    __shared__ int lbase[NB];
    int t = threadIdx.x;
    long base = (long)blockIdx.x * 2048;
    for (int b = t; b < NB; b += 256) lcnt[b] = 0;
    __syncthreads();
    int r[8], pk[8], vb[8];
    #pragma unroll
    for (int k = 0; k < 8; ++k) {
        long i = base + k * 256 + t;
        int rr = rows[i];
        r[k]  = rr;
        pk[k] = ((rr & 255) << 18) | cols[i];
        vb[k] = __float_as_int(vals[i]);
        atomicAdd(&lcnt[rr >> 8], 1);
    }
    __syncthreads();
    for (int b = t; b < NB; b += 256) {
        int c = lcnt[b];
        if (c) lbase[b] = atomicAdd(&bcur[b], c);
    }
    __syncthreads();
    #pragma unroll
    for (int k = 0; k < 8; ++k) {
        int p = atomicAdd(&lbase[r[k] >> 8], 1);
        bedges[p] = make_int2(pk[k], vb[k]);
    }
}

// one block per bucket: LDS row-histogram -> shfl scan -> offs[] + exact placement.
// All placement atomics are LDS; stores land in one contiguous ~30KB region.
__global__ __launch_bounds__(256) void fine_scatter(const int* __restrict__ boff,
                                                    const int2* __restrict__ bedges,
                                                    int* __restrict__ offs,
                                                    int2* __restrict__ edges) {
    __shared__ int hist_[256];
    __shared__ int curp[256];
    __shared__ int wsum[4], woff[4];
    int t = threadIdx.x, lane = t & 63, wid = t >> 6;
    int b = blockIdx.x;
    int s = boff[b], e = boff[b + 1];
    hist_[t] = 0;
    __syncthreads();
    for (int i = s + t; i < e; i += 256)
        atomicAdd(&hist_[((unsigned)bedges[i].x) >> 18], 1);
    __syncthreads();
    int orig = hist_[t];
    int x = orig;
    #pragma unroll
    for (int off = 1; off < 64; off <<= 1) {
        int y = __shfl_up(x, off);
        if (lane >= off) x += y;
    }
    if (lane == 63) wsum[wid] = x;
    __syncthreads();
    if (t == 0) {
        int r = 0;
        for (int i = 0; i < 4; ++i) { woff[i] = r; r += wsum[i]; }
    }
    __syncthreads();
    int excl = x - orig + woff[wid];
    int row = b * 256 + t;
    if (row < N_TOTAL) offs[row] = s + excl;
    curp[t] = s + excl;
    __syncthreads();
    for (int i = s + t; i < e; i += 256) {
        int2 rec = bedges[i];
        int rl = ((unsigned)rec.x) >> 18;
        int p = atomicAdd(&curp[rl], 1);
        edges[p] = make_int2(rec.x & 0x3FFFF, rec.y);
    }
}

// ---------------- GCN ----------------

__global__ __launch_bounds__(256) void init_ego_kernel(const float* __restrict__ uw,
                                                       const float* __restrict__ iw,
                                                       float* __restrict__ ego,
                                                       float* __restrict__ acc) {
    long i = (long)blockIdx.x * blockDim.x + threadIdx.x;  // float4 index
    const long n4 = (long)N_TOTAL * BRANCH / 4;
    if (i >= n4) return;
    long fi = i * 4;
    const long usz = (long)N_USERS * BRANCH;
    float4 v;
    if (fi < usz) v = *(const float4*)(uw + fi);
    else          v = *(const float4*)(iw + (fi - usz));
    *(float4*)(ego + fi) = v;
    *(float4*)(acc + fi) = v;
}

// 4 rows per wave (16 lanes x float4 each): one dwordx4 gather instruction keeps
// 4 independent 256B row-segments in flight; edge loop unrolled x4 on top of that
// -> up to 16 concurrent gather streams per wave.
__global__ __launch_bounds__(256) void spmv_kernel(const int* __restrict__ offs,
                                                   const int2* __restrict__ edges,
                                                   const float* __restrict__ ego_in,
                                                   float* __restrict__ ego_out,
                                                   float* __restrict__ acc,
                                                   int write_ego) {
    int wave = (blockIdx.x * 256 + threadIdx.x) >> 6;
    int lane = threadIdx.x & 63;
    int sub  = lane >> 4;          // which of the 4 rows in this wave
    int l16  = lane & 15;          // float4 slot within the row (16*4 = 64 dims)
    int row  = wave * 4 + sub;
    if (row >= N_TOTAL) return;

    int s = offs[row], e = offs[row + 1];
    f32x4 sum = {0.f, 0.f, 0.f, 0.f};

    int i  = s;
    int e4 = s + ((e - s) & ~3);
    for (; i < e4; i += 4) {
        int2 p0 = edges[i];
        int2 p1 = edges[i + 1];
        int2 p2 = edges[i + 2];
        int2 p3 = edges[i + 3];
        f32x4 g0 = *(const f32x4*)(ego_in + (long)p0.x * BRANCH + l16 * 4);
        f32x4 g1 = *(const f32x4*)(ego_in + (long)p1.x * BRANCH + l16 * 4);
        f32x4 g2 = *(const f32x4*)(ego_in + (long)p2.x * BRANCH + l16 * 4);
        f32x4 g3 = *(const f32x4*)(ego_in + (long)p3.x * BRANCH + l16 * 4);
        sum += g0 * __int_as_float(p0.y);
        sum += g1 * __int_as_float(p1.y);
        sum += g2 * __int_as_float(p2.y);
        sum += g3 * __int_as_float(p3.y);
    }
    for (; i < e; ++i) {
        int2 p = edges[i];
        f32x4 g = *(const f32x4*)(ego_in + (long)p.x * BRANCH + l16 * 4);
        sum += g * __int_as_float(p.y);
    }

    long o = (long)row * BRANCH + l16 * 4;       // 4 consecutive rows -> 1KB coalesced
    if (write_ego) *(f32x4*)(ego_out + o) = sum; // dead on last layer, skip
    f32x4 a = *(const f32x4*)(acc + o);
    a += sum;
    *(f32x4*)(acc + o) = a;
}

// ---------------- semantic branch: bf16 MFMA GEMM ----------------

__global__ __launch_bounds__(256) void wt_prep(const float* __restrict__ W,
                                               unsigned short* __restrict__ gWt) {
    int idx = blockIdx.x * 256 + threadIdx.x;  // over 64*768
    if (idx >= 64 * IN_DIM) return;
    int n = idx / IN_DIM, k = idx % IN_DIM;
    gWt[idx] = f2bf(W[(long)k * 64 + n]);
}

#define GROWS 128
#define GK 32
#define LSTR 40   // padded LDS row stride (bf16 elems): 80 B, 16B-aligned, conflict-free b128 reads

__global__ __launch_bounds__(256) void sem_gemm_mfma(const float* __restrict__ user_base,
                                                     const float* __restrict__ item_base,
                                                     const unsigned short* __restrict__ gWt,
                                                     const float* __restrict__ bias,
                                                     float* __restrict__ all_emb) {
    __shared__ unsigned short Asl[GROWS * LSTR];  // [row][k] 10 KB
    __shared__ unsigned short Wsl[64 * LSTR];     // [n][k]   5 KB

    const int tid  = threadIdx.x;
    const int row0 = blockIdx.x * GROWS;
    const int wv   = tid >> 6;
    const int lane = tid & 63;
    const int l15  = lane & 15;
    const int quad = lane >> 4;

    const int s_r = tid >> 3;        // 0..31
    const int s_c = (tid & 7) * 4;   // 0..28

    f32x4 acc[2][4];
    #pragma unroll
    for (int r = 0; r < 2; ++r)
        #pragma unroll
        for (int c = 0; c < 4; ++c)
            acc[r][c] = (f32x4){0.f, 0.f, 0.f, 0.f};

    const int wt_n  = tid >> 2;
    const int wt_c8 = (tid & 3) * 8;

    for (int kt = 0; kt < IN_DIM; kt += GK) {
        // stage A (fp32 -> bf16)
        #pragma unroll
        for (int i = 0; i < 4; ++i) {
            int r = s_r + i * 32;
            int gr = row0 + r;
            if (gr >= N_TOTAL) gr = 0;
            const float* src = (gr < N_USERS) ? (user_base + (long)gr * IN_DIM)
                                              : (item_base + (long)(gr - N_USERS) * IN_DIM);
            float4 v = *(const float4*)(src + kt + s_c);
            unsigned short* d = &Asl[r * LSTR + s_c];
            d[0] = f2bf(v.x); d[1] = f2bf(v.y); d[2] = f2bf(v.z); d[3] = f2bf(v.w);
        }
        // stage Wt (already bf16): 16 B per thread
        {
            uint4 v = *(const uint4*)(gWt + (long)wt_n * IN_DIM + kt + wt_c8);
            *(uint4*)(&Wsl[wt_n * LSTR + wt_c8]) = v;
        }
        __syncthreads();

        const int arow = wv * 32 + l15;
        short8 a0 = *(const short8*)(&Asl[arow * LSTR + quad * 8]);
        short8 a1 = *(const short8*)(&Asl[(arow + 16) * LSTR + quad * 8]);
        short8 b[4];
        #pragma unroll
        for (int c = 0; c < 4; ++c)
            b[c] = *(const short8*)(&Wsl[(c * 16 + l15) * LSTR + quad * 8]);
        #pragma unroll
        for (int c = 0; c < 4; ++c) {
            acc[0][c] = __builtin_amdgcn_mfma_f32_16x16x32_bf16(a0, b[c], acc[0][c], 0, 0, 0);
            acc[1][c] = __builtin_amdgcn_mfma_f32_16x16x32_bf16(a1, b[c], acc[1][c], 0, 0, 0);
        }
        __syncthreads();
    }

    // epilogue: D[row][col] -> all_emb[row][64+col] + bias
    #pragma unroll
    for (int r = 0; r < 2; ++r) {
        #pragma unroll
        for (int c = 0; c < 4; ++c) {
            int col = c * 16 + l15;
            float bv = bias[col];
            #pragma unroll
            for (int i = 0; i < 4; ++i) {
                int gr = row0 + wv * 32 + r * 16 + quad * 4 + i;
                if (gr < N_TOTAL)
                    all_emb[(long)gr * D2 + BRANCH + col] = acc[r][c][i] + bv;
            }
        }
    }
}

// ---------------- fusion ----------------

__global__ __launch_bounds__(256) void fuse_kernel(const float* __restrict__ acc,
                                                   float* __restrict__ all_emb) {
    int wave = (blockIdx.x * 256 + threadIdx.x) >> 6;
    int lane = threadIdx.x & 63;
    if (wave >= N_TOTAL) return;

    float c = acc[(long)wave * BRANCH + lane] * 0.25f;
    float cs = c * c;
    #pragma unroll
    for (int off = 1; off < 64; off <<= 1) cs += __shfl_xor(cs, off);
    float cn = c / fmaxf(sqrtf(cs), 1e-12f);

    float s = all_emb[(long)wave * D2 + BRANCH + lane];
    float ss = s * s;
    #pragma unroll
    for (int off = 1; off < 64; off <<= 1) ss += __shfl_xor(ss, off);
    float sn = s / fmaxf(sqrtf(ss), 1e-12f);

    float tt = cn * cn + sn * sn;
    #pragma unroll
    for (int off = 1; off < 64; off <<= 1) tt += __shfl_xor(tt, off);
    float inv = 1.0f / fmaxf(sqrtf(tt), 1e-12f);

    all_emb[(long)wave * D2 + lane]          = cn * inv;
    all_emb[(long)wave * D2 + BRANCH + lane] = sn * inv;
}

// ---------------- batch scoring + top-16 + loss ----------------

__global__ __launch_bounds__(128) void loss_kernel(const float* __restrict__ all_emb,
                                                   const int* __restrict__ uids,
                                                   const int* __restrict__ pos_iids,
                                                   const int* __restrict__ cand_ids,
                                                   float* __restrict__ out) {
    __shared__ __align__(16) float uL[128];
    __shared__ float sc[128];
    __shared__ float redv[128];
    __shared__ int   ridx[128];
    __shared__ float topvals[NEG];

    int b = blockIdx.x;
    int t = threadIdx.x;
    int uid = uids[b];
    int pid = pos_iids[b];
    const float* ib = all_emb + (long)N_USERS * D2;

    uL[t] = all_emb[(long)uid * D2 + t];
    __syncthreads();

    redv[t] = uL[t] * ib[(long)pid * D2 + t];
    __syncthreads();
    for (int st = 64; st > 0; st >>= 1) {
        if (t < st) redv[t] += redv[t + st];
        __syncthreads();
    }
    float pos_dot = redv[0];

    int cand = cand_ids[(long)b * NUM_CAND + t];
    if (cand == pid) cand = (cand + 1) % N_ITEMS;
    const float4* cr4 = (const float4*)(ib + (long)cand * D2);
    const float4* u4  = (const float4*)uL;
    float s = 0.f;
    #pragma unroll 8
    for (int k = 0; k < 32; ++k) {
        float4 a = cr4[k];
        float4 u = u4[k];
        s += a.x * u.x + a.y * u.y + a.z * u.z + a.w * u.w;
    }
    sc[t] = s;
    __syncthreads();

    for (int it = 0; it < NEG; ++it) {
        redv[t] = sc[t];
        ridx[t] = t;
        __syncthreads();
        for (int st = 64; st > 0; st >>= 1) {
            if (t < st) {
                if (redv[t + st] > redv[t]) { redv[t] = redv[t + st]; ridx[t] = ridx[t + st]; }
            }
            __syncthreads();
        }
        if (t == 0) {
            topvals[it] = redv[0];
            sc[ridx[0]] = -3.0e38f;
        }
        __syncthreads();
    }

    if (t == 0) {
        float pl = pos_dot / TEMP;
        float m = pl;
        #pragma unroll
        for (int i = 0; i < NEG; ++i) m = fmaxf(m, topvals[i] / TEMP);
        float se = __expf(pl - m);
        #pragma unroll
        for (int i = 0; i < NEG; ++i) se += __expf(topvals[i] / TEMP - m);
        float lse = m + __logf(se);
        atomicAdd(out, (lse - pl) * (1.0f / BATCH));
    }
}

// ---------------- launch ----------------

extern "C" void kernel_launch(void* const* d_in, const int* in_sizes, int n_in,
                              void* d_out, int out_size, void* d_ws, size_t ws_size,
                              hipStream_t stream) {
    const float* raw_item_embs = (const float*)d_in[0];
    const float* user_sem_base = (const float*)d_in[1];
    const float* sem_w         = (const float*)d_in[2];
    const float* sem_b         = (const float*)d_in[3];
    const float* collab_user_w = (const float*)d_in[4];
    const float* collab_item_w = (const float*)d_in[5];
    const float* adj_vals      = (const float*)d_in[6];
    const int*   adj_rows      = (const int*)d_in[7];
    const int*   adj_cols      = (const int*)d_in[8];
    const int*   uids          = (const int*)d_in[9];
    const int*   pos_iids      = (const int*)d_in[10];
    const int*   cand_ids      = (const int*)d_in[11];
    float* out = (float*)d_out;

    float* all_emb = (float*)d_ws;                           // 150000*128
    float* acc     = all_emb + (long)N_TOTAL * D2;           // 150000*64
    float* egoA    = acc  + (long)N_TOTAL * BRANCH;
    float* egoB    = egoA + (long)N_TOTAL * BRANCH;
    int*   offs    = (int*)(egoB + (long)N_TOTAL * BRANCH);  // N_TOTAL+1
    int*   bmeta   = offs + (N_TOTAL + 4);                   // former `cur` region
    int*   bcnt    = bmeta;                                  // NB
    int*   boff    = bmeta + 1024;                           // NB+1
    int*   bcur    = bmeta + 2048;                           // NB
    int2*  edges   = (int2*)(bmeta + N_TOTAL);               // N_EDGES packed (col,val)
    int*   bsums   = (int*)(edges + N_EDGES);                // legacy pad
    unsigned short* gWt = (unsigned short*)(bsums + 256);    // 64*768 bf16
    int2*  bedges  = (int2*)egoB;                            // 16.8 MB scratch, dead until init_ego

    hipMemsetAsync(bcnt, 0, 1024 * sizeof(int), stream);
    hipMemsetAsync(out, 0, sizeof(float), stream);

    // bucketed CSR build (replaces hist + 3 scan kernels + atomic scatter)
    bucket_hist   <<<BH_BLOCKS, 256, 0, stream>>>(adj_rows, bcnt);
    bucket_scan   <<<1, 256, 0, stream>>>(bcnt, boff, bcur, offs);
    bucket_scatter<<<BH_BLOCKS, 256, 0, stream>>>(adj_rows, adj_cols, adj_vals, bcur, bedges);
    fine_scatter  <<<NB, 256, 0, stream>>>(boff, bedges, offs, edges);

    // GCN
    init_ego_kernel<<<(N_TOTAL * BRANCH / 4 + 255) / 256, 256, 0, stream>>>(
        collab_user_w, collab_item_w, egoA, acc);
    const int spmv_blocks = (N_TOTAL + 15) / 16;  // 4 rows/wave, 4 waves/block -> 9375
    spmv_kernel<<<spmv_blocks, 256, 0, stream>>>(offs, edges, egoA, egoB, acc, 1);
    spmv_kernel<<<spmv_blocks, 256, 0, stream>>>(offs, edges, egoB, egoA, acc, 1);
    spmv_kernel<<<spmv_blocks, 256, 0, stream>>>(offs, edges, egoA, egoB, acc, 0);

    // semantic branch (bf16 MFMA)
    wt_prep<<<(64 * IN_DIM + 255) / 256, 256, 0, stream>>>(sem_w, gWt);
    sem_gemm_mfma<<<(N_TOTAL + GROWS - 1) / GROWS, 256, 0, stream>>>(
        user_sem_base, raw_item_embs, gWt, sem_b, all_emb);

    // fusion
    fuse_kernel<<<37500, 256, 0, stream>>>(acc, all_emb);

    // loss
    loss_kernel<<<BATCH, 128, 0, stream>>>(all_emb, uids, pos_iids, cand_ids, out);
}

// Round 3
// 924.368 us; speedup vs baseline: 1.6427x; 1.1356x over previous
//
#include <hip/hip_runtime.h>
#include <hip/hip_bf16.h>

#define N_USERS 100000
#define N_ITEMS 50000
#define N_TOTAL 150000
#define IN_DIM 768
#define BRANCH 64
#define N_EDGES 2097152
#define BATCH 4096
#define NUM_CAND 128
#define NEG 16
#define TEMP 0.1f
#define D2 128

// bucketed CSR build: 256 rows per bucket, fixed-capacity staging regions
#define NB 586                     // ceil(150000 / 256)
#define CAP 5120                   // per-bucket staging capacity (mean 3579, +25 sigma)
#define BH_BLOCKS 1024             // 1024 blocks * 256 thr * 8 edges = 2^21 = N_EDGES

typedef short short8 __attribute__((ext_vector_type(8)));
typedef float f32x4 __attribute__((ext_vector_type(4)));

__device__ __forceinline__ unsigned short f2bf(float f) {
    unsigned int u = __builtin_bit_cast(unsigned int, f);
    u += 0x7fffu + ((u >> 16) & 1u);   // round-to-nearest-even
    return (unsigned short)(u >> 16);
}

// ---------------- bucketed CSR build (2 edge passes, no hist pass) ----------------
// bucket_scatter allocates chunks in fixed-capacity bucket regions via bcnt atomics;
// bucket_scan prefix-sums the resulting counts; fine_scatter compacts + row-sorts.

__global__ __launch_bounds__(256) void bucket_scatter(const int* __restrict__ rows,
                                                      const int* __restrict__ cols,
                                                      const float* __restrict__ vals,
                                                      int* __restrict__ bcnt,
                                                      int2* __restrict__ bedges) {
    __shared__ int lcnt[NB];
    __shared__ int lbase[NB];
    int t = threadIdx.x;
    long base = (long)blockIdx.x * 2048;
    for (int b = t; b < NB; b += 256) lcnt[b] = 0;
    __syncthreads();
    int r[8], pk[8], vb[8];
    #pragma unroll
    for (int k = 0; k < 8; ++k) {
        long i = base + k * 256 + t;
        int rr = rows[i];
        r[k]  = rr;
        pk[k] = ((rr & 255) << 18) | cols[i];     // row_local<8b> | col<18b>
        vb[k] = __float_as_int(vals[i]);
        atomicAdd(&lcnt[rr >> 8], 1);
    }
    __syncthreads();
    for (int b = t; b < NB; b += 256) {
        int c = lcnt[b];
        if (c) lbase[b] = atomicAdd(&bcnt[b], c); // chunk reservation, 1 atomic/(block,bucket)
    }
    __syncthreads();
    #pragma unroll
    for (int k = 0; k < 8; ++k) {
        int b = r[k] >> 8;
        int p = atomicAdd(&lbase[b], 1);          // LDS-local placement
        bedges[(long)b * CAP + p] = make_int2(pk[k], vb[k]);
    }
}

// single block: exclusive scan of 586 bucket counts -> boff (NB+1); offs[N_TOTAL]=N_EDGES
__global__ __launch_bounds__(256) void bucket_scan(const int* __restrict__ bcnt,
                                                   int* __restrict__ boff,
                                                   int* __restrict__ offs) {
    int t = threadIdx.x;
    int fi = t * 4;
    int a0 = (fi + 0 < NB) ? bcnt[fi + 0] : 0;
    int a1 = (fi + 1 < NB) ? bcnt[fi + 1] : 0;
    int a2 = (fi + 2 < NB) ? bcnt[fi + 2] : 0;
    int a3 = (fi + 3 < NB) ? bcnt[fi + 3] : 0;
    int sm = a0 + a1 + a2 + a3;
    int x = sm;
    int lane = t & 63, wid = t >> 6;
    #pragma unroll
    for (int off = 1; off < 64; off <<= 1) {
        int y = __shfl_up(x, off);
        if (lane >= off) x += y;
    }
    __shared__ int wsum[4], woff[4];
    if (lane == 63) wsum[wid] = x;
    __syncthreads();
    if (t == 0) {
        int r = 0;
        for (int i = 0; i < 4; ++i) { woff[i] = r; r += wsum[i]; }
    }
    __syncthreads();
    int excl = (x - sm) + woff[wid];
    int p[5];
    p[0] = excl;
    p[1] = p[0] + a0;
    p[2] = p[1] + a1;
    p[3] = p[2] + a2;
    p[4] = p[3] + a3;
    #pragma unroll
    for (int k = 0; k < 4; ++k) {
        if (fi + k < NB) boff[fi + k] = p[k];
    }
    if (fi <= NB && NB < fi + 4) {       // thread holding index NB writes the total
        boff[NB] = p[NB - fi];
        offs[N_TOTAL] = p[NB - fi];      // == N_EDGES
    }
}

// one block per bucket: LDS row-histogram -> shfl scan -> offs[] + exact placement.
__global__ __launch_bounds__(256) void fine_scatter(const int* __restrict__ boff,
                                                    const int* __restrict__ bcnt,
                                                    const int2* __restrict__ bedges,
                                                    int* __restrict__ offs,
                                                    int2* __restrict__ edges) {
    __shared__ int hist_[256];
    __shared__ int curp[256];
    __shared__ int wsum[4], woff[4];
    int t = threadIdx.x, lane = t & 63, wid = t >> 6;
    int b = blockIdx.x;
    int cnt = bcnt[b];
    int s_out = boff[b];
    const int2* src = bedges + (long)b * CAP;
    hist_[t] = 0;
    __syncthreads();
    for (int i = t; i < cnt; i += 256)
        atomicAdd(&hist_[((unsigned)src[i].x) >> 18], 1);
    __syncthreads();
    int orig = hist_[t];
    int x = orig;
    #pragma unroll
    for (int off = 1; off < 64; off <<= 1) {
        int y = __shfl_up(x, off);
        if (lane >= off) x += y;
    }
    if (lane == 63) wsum[wid] = x;
    __syncthreads();
    if (t == 0) {
        int r = 0;
        for (int i = 0; i < 4; ++i) { woff[i] = r; r += wsum[i]; }
    }
    __syncthreads();
    int excl = x - orig + woff[wid];
    int row = b * 256 + t;
    if (row < N_TOTAL) offs[row] = s_out + excl;
    curp[t] = s_out + excl;
    __syncthreads();
    for (int i = t; i < cnt; i += 256) {
        int2 rec = src[i];
        int rl = ((unsigned)rec.x) >> 18;
        int p = atomicAdd(&curp[rl], 1);
        edges[p] = make_int2(rec.x & 0x3FFFF, rec.y);
    }
}

// ---------------- GCN ----------------

__global__ __launch_bounds__(256) void init_ego_kernel(const float* __restrict__ uw,
                                                       const float* __restrict__ iw,
                                                       float* __restrict__ ego) {
    long i = (long)blockIdx.x * blockDim.x + threadIdx.x;  // float4 index
    const long n4 = (long)N_TOTAL * BRANCH / 4;
    if (i >= n4) return;
    long fi = i * 4;
    const long usz = (long)N_USERS * BRANCH;
    float4 v;
    if (fi < usz) v = *(const float4*)(uw + fi);
    else          v = *(const float4*)(iw + (fi - usz));
    *(float4*)(ego + fi) = v;
}

// 4 rows per wave (16 lanes x float4 each); edge loop unrolled x4
// -> up to 16 concurrent gather streams per wave. Pure ego_in -> ego_out
// (no acc RMW: layer sum happens in fuse).
__global__ __launch_bounds__(256) void spmv_kernel(const int* __restrict__ offs,
                                                   const int2* __restrict__ edges,
                                                   const float* __restrict__ ego_in,
                                                   float* __restrict__ ego_out) {
    int wave = (blockIdx.x * 256 + threadIdx.x) >> 6;
    int lane = threadIdx.x & 63;
    int sub  = lane >> 4;          // which of the 4 rows in this wave
    int l16  = lane & 15;          // float4 slot within the row (16*4 = 64 dims)
    int row  = wave * 4 + sub;
    if (row >= N_TOTAL) return;

    int s = offs[row], e = offs[row + 1];
    f32x4 sum = {0.f, 0.f, 0.f, 0.f};

    int i  = s;
    int e4 = s + ((e - s) & ~3);
    for (; i < e4; i += 4) {
        int2 p0 = edges[i];
        int2 p1 = edges[i + 1];
        int2 p2 = edges[i + 2];
        int2 p3 = edges[i + 3];
        f32x4 g0 = *(const f32x4*)(ego_in + (long)p0.x * BRANCH + l16 * 4);
        f32x4 g1 = *(const f32x4*)(ego_in + (long)p1.x * BRANCH + l16 * 4);
        f32x4 g2 = *(const f32x4*)(ego_in + (long)p2.x * BRANCH + l16 * 4);
        f32x4 g3 = *(const f32x4*)(ego_in + (long)p3.x * BRANCH + l16 * 4);
        sum += g0 * __int_as_float(p0.y);
        sum += g1 * __int_as_float(p1.y);
        sum += g2 * __int_as_float(p2.y);
        sum += g3 * __int_as_float(p3.y);
    }
    for (; i < e; ++i) {
        int2 p = edges[i];
        f32x4 g = *(const f32x4*)(ego_in + (long)p.x * BRANCH + l16 * 4);
        sum += g * __int_as_float(p.y);
    }

    *(f32x4*)(ego_out + (long)row * BRANCH + l16 * 4) = sum;  // coalesced 1KB/wave
}

// ---------------- semantic branch: bf16 MFMA GEMM ----------------

__global__ __launch_bounds__(256) void wt_prep(const float* __restrict__ W,
                                               unsigned short* __restrict__ gWt) {
    int idx = blockIdx.x * 256 + threadIdx.x;  // over 64*768
    if (idx >= 64 * IN_DIM) return;
    int n = idx / IN_DIM, k = idx % IN_DIM;
    gWt[idx] = f2bf(W[(long)k * 64 + n]);
}

#define GROWS 128
#define GK 32
#define LSTR 40   // padded LDS row stride (bf16 elems): 80 B, 16B-aligned, conflict-free b128 reads

// GEMM over item rows only (users are handled by the 4096-row batch variant).
__global__ __launch_bounds__(256) void sem_gemm_items(const float* __restrict__ item_base,
                                                      const unsigned short* __restrict__ gWt,
                                                      const float* __restrict__ bias,
                                                      float* __restrict__ all_emb) {
    __shared__ unsigned short Asl[GROWS * LSTR];  // [row][k] 10 KB
    __shared__ unsigned short Wsl[64 * LSTR];     // [n][k]   5 KB

    const int tid  = threadIdx.x;
    const int row0 = blockIdx.x * GROWS;
    const int wv   = tid >> 6;
    const int lane = tid & 63;
    const int l15  = lane & 15;
    const int quad = lane >> 4;

    const int s_r = tid >> 3;        // 0..31
    const int s_c = (tid & 7) * 4;   // 0..28

    f32x4 acc[2][4];
    #pragma unroll
    for (int r = 0; r < 2; ++r)
        #pragma unroll
        for (int c = 0; c < 4; ++c)
            acc[r][c] = (f32x4){0.f, 0.f, 0.f, 0.f};

    const int wt_n  = tid >> 2;
    const int wt_c8 = (tid & 3) * 8;

    const float* src_[4];
    #pragma unroll
    for (int i = 0; i < 4; ++i) {
        int gr = row0 + s_r + i * 32;
        if (gr >= N_ITEMS) gr = 0;
        src_[i] = item_base + (long)gr * IN_DIM;
    }

    for (int kt = 0; kt < IN_DIM; kt += GK) {
        #pragma unroll
        for (int i = 0; i < 4; ++i) {
            int r = s_r + i * 32;
            float4 v = *(const float4*)(src_[i] + kt + s_c);
            unsigned short* d = &Asl[r * LSTR + s_c];
            d[0] = f2bf(v.x); d[1] = f2bf(v.y); d[2] = f2bf(v.z); d[3] = f2bf(v.w);
        }
        {
            uint4 v = *(const uint4*)(gWt + (long)wt_n * IN_DIM + kt + wt_c8);
            *(uint4*)(&Wsl[wt_n * LSTR + wt_c8]) = v;
        }
        __syncthreads();

        const int arow = wv * 32 + l15;
        short8 a0 = *(const short8*)(&Asl[arow * LSTR + quad * 8]);
        short8 a1 = *(const short8*)(&Asl[(arow + 16) * LSTR + quad * 8]);
        short8 b[4];
        #pragma unroll
        for (int c = 0; c < 4; ++c)
            b[c] = *(const short8*)(&Wsl[(c * 16 + l15) * LSTR + quad * 8]);
        #pragma unroll
        for (int c = 0; c < 4; ++c) {
            acc[0][c] = __builtin_amdgcn_mfma_f32_16x16x32_bf16(a0, b[c], acc[0][c], 0, 0, 0);
            acc[1][c] = __builtin_amdgcn_mfma_f32_16x16x32_bf16(a1, b[c], acc[1][c], 0, 0, 0);
        }
        __syncthreads();
    }

    #pragma unroll
    for (int r = 0; r < 2; ++r) {
        #pragma unroll
        for (int c = 0; c < 4; ++c) {
            int col = c * 16 + l15;
            float bv = bias[col];
            #pragma unroll
            for (int i = 0; i < 4; ++i) {
                int gr = row0 + wv * 32 + r * 16 + quad * 4 + i;
                if (gr < N_ITEMS)
                    all_emb[(long)(N_USERS + gr) * D2 + BRANCH + col] = acc[r][c][i] + bv;
            }
        }
    }
}

// GEMM over the 4096 batch rows, gathering user_sem_base[uids[b]].
__global__ __launch_bounds__(256) void sem_gemm_users(const float* __restrict__ user_base,
                                                      const int* __restrict__ uids,
                                                      const unsigned short* __restrict__ gWt,
                                                      const float* __restrict__ bias,
                                                      float* __restrict__ batch_u) {
    __shared__ unsigned short Asl[GROWS * LSTR];
    __shared__ unsigned short Wsl[64 * LSTR];

    const int tid  = threadIdx.x;
    const int row0 = blockIdx.x * GROWS;   // 32 blocks * 128 = 4096 exactly
    const int wv   = tid >> 6;
    const int lane = tid & 63;
    const int l15  = lane & 15;
    const int quad = lane >> 4;

    const int s_r = tid >> 3;
    const int s_c = (tid & 7) * 4;

    f32x4 acc[2][4];
    #pragma unroll
    for (int r = 0; r < 2; ++r)
        #pragma unroll
        for (int c = 0; c < 4; ++c)
            acc[r][c] = (f32x4){0.f, 0.f, 0.f, 0.f};

    const int wt_n  = tid >> 2;
    const int wt_c8 = (tid & 3) * 8;

    const float* src_[4];
    #pragma unroll
    for (int i = 0; i < 4; ++i) {
        int gr = row0 + s_r + i * 32;       // < 4096 always
        src_[i] = user_base + (long)uids[gr] * IN_DIM;
    }

    for (int kt = 0; kt < IN_DIM; kt += GK) {
        #pragma unroll
        for (int i = 0; i < 4; ++i) {
            int r = s_r + i * 32;
            float4 v = *(const float4*)(src_[i] + kt + s_c);
            unsigned short* d = &Asl[r * LSTR + s_c];
            d[0] = f2bf(v.x); d[1] = f2bf(v.y); d[2] = f2bf(v.z); d[3] = f2bf(v.w);
        }
        {
            uint4 v = *(const uint4*)(gWt + (long)wt_n * IN_DIM + kt + wt_c8);
            *(uint4*)(&Wsl[wt_n * LSTR + wt_c8]) = v;
        }
        __syncthreads();

        const int arow = wv * 32 + l15;
        short8 a0 = *(const short8*)(&Asl[arow * LSTR + quad * 8]);
        short8 a1 = *(const short8*)(&Asl[(arow + 16) * LSTR + quad * 8]);
        short8 b[4];
        #pragma unroll
        for (int c = 0; c < 4; ++c)
            b[c] = *(const short8*)(&Wsl[(c * 16 + l15) * LSTR + quad * 8]);
        #pragma unroll
        for (int c = 0; c < 4; ++c) {
            acc[0][c] = __builtin_amdgcn_mfma_f32_16x16x32_bf16(a0, b[c], acc[0][c], 0, 0, 0);
            acc[1][c] = __builtin_amdgcn_mfma_f32_16x16x32_bf16(a1, b[c], acc[1][c], 0, 0, 0);
        }
        __syncthreads();
    }

    #pragma unroll
    for (int r = 0; r < 2; ++r) {
        #pragma unroll
        for (int c = 0; c < 4; ++c) {
            int col = c * 16 + l15;
            float bv = bias[col];
            #pragma unroll
            for (int i = 0; i < 4; ++i) {
                int gr = row0 + wv * 32 + r * 16 + quad * 4 + i;  // < 4096
                batch_u[(long)gr * D2 + BRANCH + col] = acc[r][c][i] + bv;
            }
        }
    }
}

// ---------------- fusion ----------------

__device__ __forceinline__ void fuse_row(float e0, float e1, float e2, float e3,
                                         float s, float* out_c, float* out_s) {
    float c = (e0 + e1 + e2 + e3) * 0.25f;
    float cs = c * c;
    #pragma unroll
    for (int off = 1; off < 64; off <<= 1) cs += __shfl_xor(cs, off);
    float cn = c / fmaxf(sqrtf(cs), 1e-12f);

    float ss = s * s;
    #pragma unroll
    for (int off = 1; off < 64; off <<= 1) ss += __shfl_xor(ss, off);
    float sn = s / fmaxf(sqrtf(ss), 1e-12f);

    float tt = cn * cn + sn * sn;
    #pragma unroll
    for (int off = 1; off < 64; off <<= 1) tt += __shfl_xor(tt, off);
    float inv = 1.0f / fmaxf(sqrtf(tt), 1e-12f);

    *out_c = cn * inv;
    *out_s = sn * inv;
}

__global__ __launch_bounds__(256) void fuse_items(const float* __restrict__ e0,
                                                  const float* __restrict__ e1,
                                                  const float* __restrict__ e2,
                                                  const float* __restrict__ e3,
                                                  float* __restrict__ all_emb) {
    int wave = (blockIdx.x * 256 + threadIdx.x) >> 6;
    int lane = threadIdx.x & 63;
    if (wave >= N_ITEMS) return;
    long ro = (long)(N_USERS + wave) * BRANCH + lane;
    long eo = (long)(N_USERS + wave) * D2;
    float s = all_emb[eo + BRANCH + lane];
    float oc, os;
    fuse_row(e0[ro], e1[ro], e2[ro], e3[ro], s, &oc, &os);
    all_emb[eo + lane]          = oc;
    all_emb[eo + BRANCH + lane] = os;
}

__global__ __launch_bounds__(256) void fuse_users(const float* __restrict__ e0,
                                                  const float* __restrict__ e1,
                                                  const float* __restrict__ e2,
                                                  const float* __restrict__ e3,
                                                  const int* __restrict__ uids,
                                                  float* __restrict__ batch_u) {
    int wave = (blockIdx.x * 256 + threadIdx.x) >> 6;
    int lane = threadIdx.x & 63;
    if (wave >= BATCH) return;
    int uid = uids[wave];
    long ro = (long)uid * BRANCH + lane;
    long eo = (long)wave * D2;
    float s = batch_u[eo + BRANCH + lane];
    float oc, os;
    fuse_row(e0[ro], e1[ro], e2[ro], e3[ro], s, &oc, &os);
    batch_u[eo + lane]          = oc;
    batch_u[eo + BRANCH + lane] = os;
}

// ---------------- batch scoring + top-16 + loss ----------------

__global__ __launch_bounds__(128) void loss_kernel(const float* __restrict__ all_emb,
                                                   const float* __restrict__ batch_u,
                                                   const int* __restrict__ pos_iids,
                                                   const int* __restrict__ cand_ids,
                                                   float* __restrict__ out) {
    __shared__ __align__(16) float uL[128];
    __shared__ float pd[2];
    __shared__ float topv[2][NEG];

    int b = blockIdx.x;
    int t = threadIdx.x;
    int lane = t & 63, w = t >> 6;
    int pid = pos_iids[b];
    const float* ib = all_emb + (long)N_USERS * D2;

    uL[t] = batch_u[(long)b * D2 + t];
    __syncthreads();

    // pos dot: per-wave shuffle reduce over 128 dims (2 waves x 64)
    {
        float p = uL[t] * ib[(long)pid * D2 + t];
        #pragma unroll
        for (int off = 1; off < 64; off <<= 1) p += __shfl_xor(p, off);
        if (lane == 0) pd[w] = p;
    }

    // candidate scores: 1 per thread
    int cand = cand_ids[(long)b * NUM_CAND + t];
    if (cand == pid) cand = (cand + 1) % N_ITEMS;
    const float4* cr4 = (const float4*)(ib + (long)cand * D2);
    const float4* u4  = (const float4*)uL;
    float s = 0.f;
    #pragma unroll 8
    for (int k = 0; k < 32; ++k) {
        float4 a = cr4[k];
        float4 u = u4[k];
        s += a.x * u.x + a.y * u.y + a.z * u.z + a.w * u.w;
    }

    // wave-synchronous top-16 per wave via shfl argmax (no block barriers inside)
    float val = s;
    for (int it = 0; it < NEG; ++it) {
        float m = val; int ml = lane;
        #pragma unroll
        for (int off = 1; off < 64; off <<= 1) {
            float ov = __shfl_xor(m, off);
            int   ol = __shfl_xor(ml, off);
            if (ov > m || (ov == m && ol < ml)) { m = ov; ml = ol; }
        }
        if (lane == 0) topv[w][it] = m;   // descending order
        if (lane == ml) val = -3.0e38f;
    }
    __syncthreads();

    if (t == 0) {
        float pos_dot = pd[0] + pd[1];
        float pl = pos_dot * (1.0f / TEMP);
        // merge two descending 16-lists, keep global top-16
        float sel[NEG];
        int i = 0, j = 0;
        #pragma unroll
        for (int k = 0; k < NEG; ++k) {
            float v0 = (i < NEG) ? topv[0][i] : -3.4e38f;
            float v1 = (j < NEG) ? topv[1][j] : -3.4e38f;
            if (v0 >= v1) { sel[k] = v0; ++i; } else { sel[k] = v1; ++j; }
        }
        float m = pl;
        #pragma unroll
        for (int k = 0; k < NEG; ++k) m = fmaxf(m, sel[k] * (1.0f / TEMP));
        float se = __expf(pl - m);
        #pragma unroll
        for (int k = 0; k < NEG; ++k) se += __expf(sel[k] * (1.0f / TEMP) - m);
        float lse = m + __logf(se);
        atomicAdd(out, (lse - pl) * (1.0f / BATCH));
    }
}

// ---------------- launch ----------------

extern "C" void kernel_launch(void* const* d_in, const int* in_sizes, int n_in,
                              void* d_out, int out_size, void* d_ws, size_t ws_size,
                              hipStream_t stream) {
    const float* raw_item_embs = (const float*)d_in[0];
    const float* user_sem_base = (const float*)d_in[1];
    const float* sem_w         = (const float*)d_in[2];
    const float* sem_b         = (const float*)d_in[3];
    const float* collab_user_w = (const float*)d_in[4];
    const float* collab_item_w = (const float*)d_in[5];
    const float* adj_vals      = (const float*)d_in[6];
    const int*   adj_rows      = (const int*)d_in[7];
    const int*   adj_cols      = (const int*)d_in[8];
    const int*   uids          = (const int*)d_in[9];
    const int*   pos_iids      = (const int*)d_in[10];
    const int*   cand_ids      = (const int*)d_in[11];
    float* out = (float*)d_out;

    float* all_emb = (float*)d_ws;                            // N_TOTAL*128 (items half used)
    float* batch_u = all_emb + (long)N_TOTAL * D2;            // BATCH*128
    float* egoA    = batch_u + (long)BATCH * D2;              // layer 0 (init)
    float* egoB    = egoA + (long)N_TOTAL * BRANCH;           // layer 1
    float* egoC    = egoB + (long)N_TOTAL * BRANCH;           // layer 2
    float* egoD    = egoC + (long)N_TOTAL * BRANCH;           // layer 3
    int*   offs    = (int*)(egoD + (long)N_TOTAL * BRANCH);   // N_TOTAL+1 (+pad)
    int*   bcnt    = offs + (N_TOTAL + 4);                    // NB (pad 1024)
    int*   boff    = bcnt + 1024;                             // NB+1 (pad 1024)
    int2*  edges   = (int2*)(boff + 1024);                    // N_EDGES packed (col,val)
    unsigned short* gWt = (unsigned short*)(edges + N_EDGES); // 64*768 bf16
    int2*  bedges  = (int2*)(gWt + 64 * IN_DIM);              // NB*CAP staging (24 MB)

    hipMemsetAsync(bcnt, 0, 1024 * sizeof(int), stream);
    hipMemsetAsync(out, 0, sizeof(float), stream);

    // bucketed CSR build (single edge pass + compact pass)
    bucket_scatter<<<BH_BLOCKS, 256, 0, stream>>>(adj_rows, adj_cols, adj_vals, bcnt, bedges);
    bucket_scan   <<<1, 256, 0, stream>>>(bcnt, boff, offs);
    fine_scatter  <<<NB, 256, 0, stream>>>(boff, bcnt, bedges, offs, edges);

    // GCN: per-layer outputs, summed in fuse (no acc RMW)
    init_ego_kernel<<<(N_TOTAL * BRANCH / 4 + 255) / 256, 256, 0, stream>>>(
        collab_user_w, collab_item_w, egoA);
    const int spmv_blocks = (N_TOTAL + 15) / 16;  // 4 rows/wave, 4 waves/block
    spmv_kernel<<<spmv_blocks, 256, 0, stream>>>(offs, edges, egoA, egoB);
    spmv_kernel<<<spmv_blocks, 256, 0, stream>>>(offs, edges, egoB, egoC);
    spmv_kernel<<<spmv_blocks, 256, 0, stream>>>(offs, edges, egoC, egoD);

    // semantic branch: items + gathered batch users only (dead rows skipped)
    wt_prep<<<(64 * IN_DIM + 255) / 256, 256, 0, stream>>>(sem_w, gWt);
    sem_gemm_items<<<(N_ITEMS + GROWS - 1) / GROWS, 256, 0, stream>>>(
        raw_item_embs, gWt, sem_b, all_emb);
    sem_gemm_users<<<BATCH / GROWS, 256, 0, stream>>>(
        user_sem_base, uids, gWt, sem_b, batch_u);

    // fusion (items + batch users)
    fuse_items<<<(N_ITEMS + 3) / 4, 256, 0, stream>>>(egoA, egoB, egoC, egoD, all_emb);
    fuse_users<<<(BATCH + 3) / 4, 256, 0, stream>>>(egoA, egoB, egoC, egoD, uids, batch_u);

    // loss
    loss_kernel<<<BATCH, 128, 0, stream>>>(all_emb, batch_u, pos_iids, cand_ids, out);
}